// Round 1
// baseline (119.753 us; speedup 1.0000x reference)
//
#include <hip/hip_runtime.h>
#include <hip/hip_bf16.h>

constexpr int BATCH = 256;
constexpr int VOCAB = 128000;
constexpr int K = 256;
constexpr int BINS = 8192;      // top 13 bits of monotone key
constexpr int SHIFT = 19;       // 32 - 13
constexpr int CAND = 2048;      // candidate buffer (power of two for bitonic)
constexpr float IGNORED_C = -3000.0f;

// order-preserving f32 -> u32 map (larger float => larger key)
__device__ __forceinline__ unsigned mono(unsigned u) {
    return (u & 0x80000000u) ? ~u : (u | 0x80000000u);
}
__device__ __forceinline__ float inv_mono(unsigned k) {
    unsigned u = (k & 0x80000000u) ? (k ^ 0x80000000u) : ~k;
    return __uint_as_float(u);
}

__global__ __launch_bounds__(1024)
void sampler_stage1(const float* __restrict__ logits,
                    const float* __restrict__ params,
                    float* __restrict__ ws_v,
                    float* __restrict__ ws_csum,
                    int* __restrict__ ws_idx,
                    float* __restrict__ ws_p0)
{
    __shared__ unsigned hist[BINS];
    __shared__ unsigned gsum[128];
    __shared__ unsigned long long cand[CAND];
    __shared__ unsigned ccount;
    __shared__ int tbin;
    __shared__ float sv[K];
    __shared__ float se[K];
    __shared__ int   sidx[K];
    __shared__ float sred;

    const int row = blockIdx.x;
    const int tid = threadIdx.x;
    const float4* rp4 = reinterpret_cast<const float4*>(logits + (size_t)row * VOCAB);

    for (int i = tid; i < BINS; i += 1024) hist[i] = 0u;
    __syncthreads();

    // ---- pass 1: histogram of top-13-bit keys ----
    for (int i = tid; i < VOCAB / 4; i += 1024) {
        float4 v = rp4[i];
        atomicAdd(&hist[mono(__float_as_uint(v.x)) >> SHIFT], 1u);
        atomicAdd(&hist[mono(__float_as_uint(v.y)) >> SHIFT], 1u);
        atomicAdd(&hist[mono(__float_as_uint(v.z)) >> SHIFT], 1u);
        atomicAdd(&hist[mono(__float_as_uint(v.w)) >> SHIFT], 1u);
    }
    __syncthreads();

    // ---- find threshold bin t: largest bin with suffix-count >= K ----
    if (tid < 128) {
        unsigned s = 0;
        for (int i = 0; i < 64; ++i) s += hist[tid * 64 + i];
        gsum[tid] = s;
    }
    __syncthreads();
    if (tid == 0) {
        unsigned acc = 0;
        int g = 127;
        for (; g > 0; --g) {
            if (acc + gsum[g] >= (unsigned)K) break;
            acc += gsum[g];
        }
        int t = g * 64;
        for (int bin = g * 64 + 63; bin >= g * 64; --bin) {
            acc += hist[bin];
            if (acc >= (unsigned)K) { t = bin; break; }
        }
        tbin = t;
        ccount = 0u;
    }
    __syncthreads();

    // ---- pass 2: collect candidates with bin >= tbin ----
    const unsigned tb = (unsigned)tbin;
    for (int i = tid; i < VOCAB / 4; i += 1024) {
        float4 v = rp4[i];
        const int base = i * 4;
        unsigned k0 = mono(__float_as_uint(v.x));
        unsigned k1 = mono(__float_as_uint(v.y));
        unsigned k2 = mono(__float_as_uint(v.z));
        unsigned k3 = mono(__float_as_uint(v.w));
        if ((k0 >> SHIFT) >= tb) { unsigned p = atomicAdd(&ccount, 1u); if (p < CAND) cand[p] = ((unsigned long long)k0 << 32) | (unsigned)(~(base + 0)); }
        if ((k1 >> SHIFT) >= tb) { unsigned p = atomicAdd(&ccount, 1u); if (p < CAND) cand[p] = ((unsigned long long)k1 << 32) | (unsigned)(~(base + 1)); }
        if ((k2 >> SHIFT) >= tb) { unsigned p = atomicAdd(&ccount, 1u); if (p < CAND) cand[p] = ((unsigned long long)k2 << 32) | (unsigned)(~(base + 2)); }
        if ((k3 >> SHIFT) >= tb) { unsigned p = atomicAdd(&ccount, 1u); if (p < CAND) cand[p] = ((unsigned long long)k3 << 32) | (unsigned)(~(base + 3)); }
    }
    __syncthreads();
    for (int i = tid; i < CAND; i += 1024)
        if ((unsigned)i >= ccount) cand[i] = 0ull;
    __syncthreads();

    // ---- bitonic sort, descending (value desc, idx asc via ~idx in low word) ----
    for (int k = 2; k <= CAND; k <<= 1) {
        for (int j = k >> 1; j > 0; j >>= 1) {
            for (int i = tid; i < CAND; i += 1024) {
                int ixj = i ^ j;
                if (ixj > i) {
                    unsigned long long a = cand[i], b = cand[ixj];
                    bool sw = ((i & k) == 0) ? (a < b) : (a > b);
                    if (sw) { cand[i] = b; cand[ixj] = a; }
                }
            }
            __syncthreads();
        }
    }

    // ---- per-row pipeline: topk-mask -> /temp -> softmax -> cumsum ----
    const float topk_f = params[row * 3 + 0];
    const float temp   = params[row * 3 + 2];
    if (tid < K) {
        unsigned long long c = cand[tid];
        unsigned key = (unsigned)(c >> 32);
        float val = inv_mono(key);
        sidx[tid] = (int)(~(unsigned)c);
        float v = (((float)tid) >= topk_f) ? IGNORED_C : val;
        sv[tid] = v / temp;
    }
    __syncthreads();
    if (tid == 0) {
        float m = sv[0];
        for (int i = 1; i < K; ++i) m = fmaxf(m, sv[i]);
        sred = m;
    }
    __syncthreads();
    if (tid < K) se[tid] = expf(sv[tid] - sred);
    __syncthreads();
    if (tid == 0) {
        float s = 0.f;
        for (int i = 0; i < K; ++i) s += se[i];
        sred = s;
    }
    __syncthreads();
    if (tid < K) se[tid] = se[tid] / sred;   // probs
    __syncthreads();
    if (tid == 0) {
        float c = 0.f;
        for (int i = 0; i < K; ++i) { c += se[i]; se[i] = c; }  // csum in place
    }
    __syncthreads();
    if (tid < K) {
        ws_v[row * K + tid]    = sv[tid];
        ws_csum[row * K + tid] = se[tid];
        ws_idx[row * K + tid]  = sidx[tid];
    }
    if (tid == 0) ws_p0[row] = se[0];   // csum[0] == probs[0]
}

__global__ __launch_bounds__(256)
void sampler_stage2(const float* __restrict__ params,
                    const float* __restrict__ rand_u,
                    const float* __restrict__ ws_v,
                    const float* __restrict__ ws_csum,
                    const int* __restrict__ ws_idx,
                    const float* __restrict__ ws_p0,
                    int* __restrict__ out)
{
    const int row = blockIdx.x;
    const int tid = threadIdx.x;
    __shared__ float sa[K];
    __shared__ float sb[K];
    __shared__ float sred;
    __shared__ int scnt;

    // global min over all rows of csum == min_b probs[b,0]
    sa[tid] = ws_p0[tid];
    __syncthreads();
    if (tid == 0) {
        float m = sa[0];
        for (int i = 1; i < K; ++i) m = fminf(m, sa[i]);
        sred = m;
    }
    __syncthreads();
    const float tpe = fmaxf(sred, params[row * 3 + 1]);
    const float csum = ws_csum[row * K + tid];
    const float v = ws_v[row * K + tid];
    const float v2 = ((csum > tpe) && (tid != 0)) ? IGNORED_C : v;
    __syncthreads();

    sa[tid] = v2;
    __syncthreads();
    if (tid == 0) {
        float m = sa[0];
        for (int i = 1; i < K; ++i) m = fmaxf(m, sa[i]);
        sred = m;
    }
    __syncthreads();
    const float e = expf(v2 - sred);
    sb[tid] = e;
    __syncthreads();
    if (tid == 0) {
        float s = 0.f;
        for (int i = 0; i < K; ++i) s += sb[i];
        sred = s;
    }
    __syncthreads();
    const float p = e / sred;
    sb[tid] = p;
    __syncthreads();
    if (tid == 0) {
        float c = 0.f;
        for (int i = 0; i < K; ++i) { c += sb[i]; sb[i] = c; }  // csum2
    }
    __syncthreads();
    const float ru = rand_u[row];
    const int myc = (ru > sb[tid]) ? 1 : 0;
    if (tid == 0) scnt = 0;
    __syncthreads();
    atomicAdd(&scnt, myc);
    __syncthreads();
    if (tid == 0) {
        int sel = scnt;
        if (sel > K - 1) sel = K - 1;
        out[row] = ws_idx[row * K + sel];
    }
}

extern "C" void kernel_launch(void* const* d_in, const int* in_sizes, int n_in,
                              void* d_out, int out_size, void* d_ws, size_t ws_size,
                              hipStream_t stream) {
    const float* logits = (const float*)d_in[0];
    const float* params = (const float*)d_in[1];
    const float* randu  = (const float*)d_in[2];
    char* ws = (char*)d_ws;
    float* ws_v    = (float*)(ws);
    float* ws_csum = (float*)(ws + (size_t)BATCH * K * 4);
    int*   ws_idx  = (int*)  (ws + (size_t)2 * BATCH * K * 4);
    float* ws_p0   = (float*)(ws + (size_t)3 * BATCH * K * 4);
    int* out = (int*)d_out;

    hipLaunchKernelGGL(sampler_stage1, dim3(BATCH), dim3(1024), 0, stream,
                       logits, params, ws_v, ws_csum, ws_idx, ws_p0);
    hipLaunchKernelGGL(sampler_stage2, dim3(BATCH), dim3(256), 0, stream,
                       params, randu, ws_v, ws_csum, ws_idx, ws_p0, out);
}

// Round 2
// 94.804 us; speedup vs baseline: 1.2632x; 1.2632x over previous
//
#include <hip/hip_runtime.h>
#include <hip/hip_bf16.h>

constexpr int BATCH = 256;
constexpr int VOCAB = 128000;
constexpr int K = 256;
constexpr float IGNORED_C = -3000.0f;

// fast path params
constexpr int NCHUNK = 8;
constexpr int CHUNK = VOCAB / NCHUNK;   // 16000
constexpr int BINS = 8192;              // top 13 bits of monotone key
constexpr int SHIFT = 19;
constexpr int CAP = 512;                // per-chunk candidate cap (sort width)

// fallback path params
constexpr int FB_BINS = 8192;
constexpr int FB_CAND = 2048;

// order-preserving f32 -> u32 map (larger float => larger key)
__device__ __forceinline__ unsigned mono(unsigned u) {
    return (u & 0x80000000u) ? ~u : (u | 0x80000000u);
}
__device__ __forceinline__ float inv_mono(unsigned k) {
    unsigned u = (k & 0x80000000u) ? (k ^ 0x80000000u) : ~k;
    return __uint_as_float(u);
}

// ============================================================================
// K1: per (row, chunk) exact top-256 (value desc, idx asc), sorted, u64 keys
// ============================================================================
__global__ __launch_bounds__(512)
void k1_topk_chunk(const float* __restrict__ logits,
                   unsigned long long* __restrict__ ws_cand)
{
    __shared__ unsigned hist[BINS];
    __shared__ unsigned long long cand[CAP];
    __shared__ unsigned part[512];
    __shared__ unsigned ccount;
    __shared__ int tbin;

    const int tid = threadIdx.x;
    const int row = blockIdx.x >> 3;            // NCHUNK == 8
    const int chunk = blockIdx.x & (NCHUNK - 1);
    const float4* rp4 = reinterpret_cast<const float4*>(
        logits + (size_t)row * VOCAB + (size_t)chunk * CHUNK);
    constexpr int N4 = CHUNK / 4;               // 4000

    for (int i = tid; i < BINS; i += 512) hist[i] = 0u;
    __syncthreads();

    // pass 1: histogram of top-13-bit keys
    for (int i = tid; i < N4; i += 512) {
        float4 v = rp4[i];
        atomicAdd(&hist[mono(__float_as_uint(v.x)) >> SHIFT], 1u);
        atomicAdd(&hist[mono(__float_as_uint(v.y)) >> SHIFT], 1u);
        atomicAdd(&hist[mono(__float_as_uint(v.z)) >> SHIFT], 1u);
        atomicAdd(&hist[mono(__float_as_uint(v.w)) >> SHIFT], 1u);
    }
    __syncthreads();

    // threshold bin: largest t with suffix-count >= K
    {
        unsigned s = 0;
        #pragma unroll
        for (int i = 0; i < 16; ++i) s += hist[tid * 16 + i];
        part[tid] = s;
    }
    __syncthreads();
    if (tid == 0) {
        unsigned acc = 0;
        int g = 511;
        for (; g > 0; --g) {
            if (acc + part[g] >= (unsigned)K) break;
            acc += part[g];
        }
        int t = g * 16;
        unsigned a2 = acc;
        for (int b = g * 16 + 15; b >= g * 16; --b) {
            a2 += hist[b];
            if (a2 >= (unsigned)K) { t = b; break; }
        }
        tbin = t;
        ccount = 0u;
    }
    __syncthreads();

    // pass 2: collect candidates with bin >= tbin (from L2/L3)
    const unsigned tb = (unsigned)tbin;
    const int gbase = chunk * CHUNK;
    for (int i = tid; i < N4; i += 512) {
        float4 v = rp4[i];
        const int base = gbase + i * 4;
        unsigned kk[4] = { mono(__float_as_uint(v.x)), mono(__float_as_uint(v.y)),
                           mono(__float_as_uint(v.z)), mono(__float_as_uint(v.w)) };
        #pragma unroll
        for (int c = 0; c < 4; ++c) {
            if ((kk[c] >> SHIFT) >= tb) {
                unsigned p = atomicAdd(&ccount, 1u);
                if (p < CAP)
                    cand[p] = ((unsigned long long)kk[c] << 32) | (unsigned)(~(base + c));
            }
        }
    }
    __syncthreads();
    for (int i = tid; i < CAP; i += 512)
        if ((unsigned)i >= ccount) cand[i] = 0ull;
    __syncthreads();

    // bitonic sort 512 descending (1 element per thread)
    for (int kk2 = 2; kk2 <= CAP; kk2 <<= 1) {
        for (int j = kk2 >> 1; j > 0; j >>= 1) {
            const int i = tid, ixj = i ^ j;
            if (ixj > i) {
                unsigned long long a = cand[i], b = cand[ixj];
                bool sw = ((i & kk2) == 0) ? (a < b) : (a > b);
                if (sw) { cand[i] = b; cand[ixj] = a; }
            }
            __syncthreads();
        }
    }

    if (tid < K) ws_cand[(size_t)blockIdx.x * K + tid] = cand[tid];
}

// ============================================================================
// K2: per row merge 8 sorted runs (bitonic merge stages only) + pipeline
// ============================================================================
__global__ __launch_bounds__(1024)
void k2_merge(const float* __restrict__ params,
              const unsigned long long* __restrict__ ws_cand,
              float* __restrict__ ws_v, float* __restrict__ ws_csum,
              int* __restrict__ ws_idx, float* __restrict__ ws_p0)
{
    constexpr int N = NCHUNK * K;   // 2048
    __shared__ unsigned long long cand[N];
    __shared__ float red[K];
    __shared__ float sc[K];

    const int row = blockIdx.x;
    const int tid = threadIdx.x;

    // load; reverse odd runs so runs alternate desc/asc (valid bitonic state k=256)
    for (int i = tid; i < N; i += 1024) {
        const int c = i >> 8, pos = i & (K - 1);
        unsigned long long v = ws_cand[(size_t)row * N + i];
        const int dest = (c & 1) ? ((c << 8) | (K - 1 - pos)) : i;
        cand[dest] = v;
    }
    __syncthreads();

    // bitonic merge stages k = 512, 1024, 2048 (descending overall)
    for (int kk2 = 2 * K; kk2 <= N; kk2 <<= 1) {
        for (int j = kk2 >> 1; j > 0; j >>= 1) {
            for (int i = tid; i < N; i += 1024) {
                const int ixj = i ^ j;
                if (ixj > i) {
                    unsigned long long a = cand[i], b = cand[ixj];
                    bool sw = ((i & kk2) == 0) ? (a < b) : (a > b);
                    if (sw) { cand[i] = b; cand[ixj] = a; }
                }
            }
            __syncthreads();
        }
    }

    // pipeline on top-256: topk-mask -> /temp -> softmax -> cumsum
    const bool act = tid < K;
    const float topk_f = params[row * 3 + 0];
    const float temp   = params[row * 3 + 2];
    float v = 0.f;
    int myidx = 0;
    if (act) {
        unsigned long long c = cand[tid];
        float val = inv_mono((unsigned)(c >> 32));
        myidx = (int)(~(unsigned)c);
        float x = (((float)tid) >= topk_f) ? IGNORED_C : val;
        v = x / temp;
        red[tid] = v;
    }
    __syncthreads();
    for (int s = K / 2; s > 0; s >>= 1) {
        if (tid < s) red[tid] = fmaxf(red[tid], red[tid + s]);
        __syncthreads();
    }
    const float m = red[0];
    __syncthreads();
    const float e = act ? expf(v - m) : 0.f;
    if (act) red[tid] = e;
    __syncthreads();
    for (int s = K / 2; s > 0; s >>= 1) {
        if (tid < s) red[tid] += red[tid + s];
        __syncthreads();
    }
    const float ssum = red[0];
    __syncthreads();
    const float p = e / ssum;
    if (act) sc[tid] = p;
    __syncthreads();
    for (int off = 1; off < K; off <<= 1) {
        float t = 0.f;
        if (act && tid >= off) t = sc[tid - off];
        __syncthreads();
        if (act) sc[tid] += t;
        __syncthreads();
    }
    if (act) {
        ws_v[row * K + tid]    = v;
        ws_csum[row * K + tid] = sc[tid];
        ws_idx[row * K + tid]  = myidx;
    }
    if (tid == 0) ws_p0[row] = p;   // probs[0] == csum[0]
}

// ============================================================================
// K3: global-min(p0) -> top-p mask -> softmax -> cumsum -> sample
// ============================================================================
__global__ __launch_bounds__(K)
void k3_sample(const float* __restrict__ params,
               const float* __restrict__ rand_u,
               const float* __restrict__ ws_v,
               const float* __restrict__ ws_csum,
               const int* __restrict__ ws_idx,
               const float* __restrict__ ws_p0,
               int* __restrict__ out)
{
    __shared__ float red[K];
    __shared__ float sc[K];
    const int row = blockIdx.x;
    const int tid = threadIdx.x;

    red[tid] = ws_p0[tid];          // BATCH == 256 == blockDim
    __syncthreads();
    for (int s = K / 2; s > 0; s >>= 1) {
        if (tid < s) red[tid] = fminf(red[tid], red[tid + s]);
        __syncthreads();
    }
    const float tpe = fmaxf(red[0], params[row * 3 + 1]);
    __syncthreads();

    const float csum = ws_csum[row * K + tid];
    const float v0   = ws_v[row * K + tid];
    const float v2 = ((csum > tpe) && (tid != 0)) ? IGNORED_C : v0;
    red[tid] = v2;
    __syncthreads();
    for (int s = K / 2; s > 0; s >>= 1) {
        if (tid < s) red[tid] = fmaxf(red[tid], red[tid + s]);
        __syncthreads();
    }
    const float m = red[0];
    __syncthreads();
    const float e = expf(v2 - m);
    red[tid] = e;
    __syncthreads();
    for (int s = K / 2; s > 0; s >>= 1) {
        if (tid < s) red[tid] += red[tid + s];
        __syncthreads();
    }
    const float ssum = red[0];
    __syncthreads();
    const float p = e / ssum;
    sc[tid] = p;
    __syncthreads();
    for (int off = 1; off < K; off <<= 1) {
        float t = (tid >= off) ? sc[tid - off] : 0.f;
        __syncthreads();
        sc[tid] += t;
        __syncthreads();
    }
    const float ru = rand_u[row];
    red[tid] = (ru > sc[tid]) ? 1.f : 0.f;
    __syncthreads();
    for (int s = K / 2; s > 0; s >>= 1) {
        if (tid < s) red[tid] += red[tid + s];
        __syncthreads();
    }
    if (tid == 0) {
        int sel = (int)red[0];
        if (sel > K - 1) sel = K - 1;
        out[row] = ws_idx[row * K + sel];
    }
}

// ============================================================================
// Fallback (round-1 proven): single block per row, used only if ws too small
// ============================================================================
__global__ __launch_bounds__(1024)
void fb_stage1(const float* __restrict__ logits,
               const float* __restrict__ params,
               float* __restrict__ ws_v,
               float* __restrict__ ws_csum,
               int* __restrict__ ws_idx,
               float* __restrict__ ws_p0)
{
    __shared__ unsigned hist[FB_BINS];
    __shared__ unsigned gsum[128];
    __shared__ unsigned long long cand[FB_CAND];
    __shared__ unsigned ccount;
    __shared__ int tbin;
    __shared__ float sv[K];
    __shared__ float se[K];
    __shared__ int   sidx[K];
    __shared__ float sred;

    const int row = blockIdx.x;
    const int tid = threadIdx.x;
    const float4* rp4 = reinterpret_cast<const float4*>(logits + (size_t)row * VOCAB);

    for (int i = tid; i < FB_BINS; i += 1024) hist[i] = 0u;
    __syncthreads();
    for (int i = tid; i < VOCAB / 4; i += 1024) {
        float4 v = rp4[i];
        atomicAdd(&hist[mono(__float_as_uint(v.x)) >> SHIFT], 1u);
        atomicAdd(&hist[mono(__float_as_uint(v.y)) >> SHIFT], 1u);
        atomicAdd(&hist[mono(__float_as_uint(v.z)) >> SHIFT], 1u);
        atomicAdd(&hist[mono(__float_as_uint(v.w)) >> SHIFT], 1u);
    }
    __syncthreads();
    if (tid < 128) {
        unsigned s = 0;
        for (int i = 0; i < 64; ++i) s += hist[tid * 64 + i];
        gsum[tid] = s;
    }
    __syncthreads();
    if (tid == 0) {
        unsigned acc = 0;
        int g = 127;
        for (; g > 0; --g) {
            if (acc + gsum[g] >= (unsigned)K) break;
            acc += gsum[g];
        }
        int t = g * 64;
        for (int bin = g * 64 + 63; bin >= g * 64; --bin) {
            acc += hist[bin];
            if (acc >= (unsigned)K) { t = bin; break; }
        }
        tbin = t;
        ccount = 0u;
    }
    __syncthreads();
    const unsigned tb = (unsigned)tbin;
    for (int i = tid; i < VOCAB / 4; i += 1024) {
        float4 v = rp4[i];
        const int base = i * 4;
        unsigned kk[4] = { mono(__float_as_uint(v.x)), mono(__float_as_uint(v.y)),
                           mono(__float_as_uint(v.z)), mono(__float_as_uint(v.w)) };
        #pragma unroll
        for (int c = 0; c < 4; ++c) {
            if ((kk[c] >> SHIFT) >= tb) {
                unsigned p = atomicAdd(&ccount, 1u);
                if (p < FB_CAND)
                    cand[p] = ((unsigned long long)kk[c] << 32) | (unsigned)(~(base + c));
            }
        }
    }
    __syncthreads();
    for (int i = tid; i < FB_CAND; i += 1024)
        if ((unsigned)i >= ccount) cand[i] = 0ull;
    __syncthreads();
    for (int k = 2; k <= FB_CAND; k <<= 1) {
        for (int j = k >> 1; j > 0; j >>= 1) {
            for (int i = tid; i < FB_CAND; i += 1024) {
                int ixj = i ^ j;
                if (ixj > i) {
                    unsigned long long a = cand[i], b = cand[ixj];
                    bool sw = ((i & k) == 0) ? (a < b) : (a > b);
                    if (sw) { cand[i] = b; cand[ixj] = a; }
                }
            }
            __syncthreads();
        }
    }
    const float topk_f = params[row * 3 + 0];
    const float temp   = params[row * 3 + 2];
    if (tid < K) {
        unsigned long long c = cand[tid];
        float val = inv_mono((unsigned)(c >> 32));
        sidx[tid] = (int)(~(unsigned)c);
        float v = (((float)tid) >= topk_f) ? IGNORED_C : val;
        sv[tid] = v / temp;
    }
    __syncthreads();
    if (tid == 0) {
        float mm = sv[0];
        for (int i = 1; i < K; ++i) mm = fmaxf(mm, sv[i]);
        sred = mm;
    }
    __syncthreads();
    if (tid < K) se[tid] = expf(sv[tid] - sred);
    __syncthreads();
    if (tid == 0) {
        float s = 0.f;
        for (int i = 0; i < K; ++i) s += se[i];
        sred = s;
    }
    __syncthreads();
    if (tid < K) se[tid] = se[tid] / sred;
    __syncthreads();
    if (tid == 0) {
        float c = 0.f;
        for (int i = 0; i < K; ++i) { c += se[i]; se[i] = c; }
    }
    __syncthreads();
    if (tid < K) {
        ws_v[row * K + tid]    = sv[tid];
        ws_csum[row * K + tid] = se[tid];
        ws_idx[row * K + tid]  = sidx[tid];
    }
    if (tid == 0) ws_p0[row] = se[0];
}

extern "C" void kernel_launch(void* const* d_in, const int* in_sizes, int n_in,
                              void* d_out, int out_size, void* d_ws, size_t ws_size,
                              hipStream_t stream) {
    const float* logits = (const float*)d_in[0];
    const float* params = (const float*)d_in[1];
    const float* randu  = (const float*)d_in[2];
    int* out = (int*)d_out;
    char* ws = (char*)d_ws;

    const size_t cand_bytes = (size_t)BATCH * NCHUNK * K * 8;          // 4 MB
    const size_t tail_bytes = (size_t)3 * BATCH * K * 4 + BATCH * 4;   // 769 KB
    if (ws_size >= cand_bytes + tail_bytes) {
        unsigned long long* ws_cand = (unsigned long long*)ws;
        char* p = ws + cand_bytes;
        float* ws_v    = (float*)(p);
        float* ws_csum = (float*)(p + (size_t)BATCH * K * 4);
        int*   ws_idx  = (int*)  (p + (size_t)2 * BATCH * K * 4);
        float* ws_p0   = (float*)(p + (size_t)3 * BATCH * K * 4);
        hipLaunchKernelGGL(k1_topk_chunk, dim3(BATCH * NCHUNK), dim3(512), 0, stream,
                           logits, ws_cand);
        hipLaunchKernelGGL(k2_merge, dim3(BATCH), dim3(1024), 0, stream,
                           params, ws_cand, ws_v, ws_csum, ws_idx, ws_p0);
        hipLaunchKernelGGL(k3_sample, dim3(BATCH), dim3(K), 0, stream,
                           params, randu, ws_v, ws_csum, ws_idx, ws_p0, out);
    } else {
        float* ws_v    = (float*)(ws);
        float* ws_csum = (float*)(ws + (size_t)BATCH * K * 4);
        int*   ws_idx  = (int*)  (ws + (size_t)2 * BATCH * K * 4);
        float* ws_p0   = (float*)(ws + (size_t)3 * BATCH * K * 4);
        hipLaunchKernelGGL(fb_stage1, dim3(BATCH), dim3(1024), 0, stream,
                           logits, params, ws_v, ws_csum, ws_idx, ws_p0);
        hipLaunchKernelGGL(k3_sample, dim3(BATCH), dim3(K), 0, stream,
                           params, randu, ws_v, ws_csum, ws_idx, ws_p0, out);
    }
}

// Round 3
// 72.041 us; speedup vs baseline: 1.6623x; 1.3160x over previous
//
#include <hip/hip_runtime.h>
#include <hip/hip_bf16.h>

constexpr int BATCH = 256;
constexpr int VOCAB = 128000;
constexpr int K = 256;
constexpr float IGNORED_C = -3000.0f;

// fast path params
constexpr int NCHUNK = 8;
constexpr int CHUNK = VOCAB / NCHUNK;   // 16000
constexpr int BINS = 8192;              // top 13 bits of monotone key
constexpr int SHIFT = 19;
constexpr int CAP = 512;                // per-chunk candidate cap == blockDim

// fallback path params
constexpr int FB_BINS = 8192;
constexpr int FB_CAND = 2048;

// order-preserving f32 -> u32 map (larger float => larger key)
__device__ __forceinline__ unsigned mono(unsigned u) {
    return (u & 0x80000000u) ? ~u : (u | 0x80000000u);
}
__device__ __forceinline__ float inv_mono(unsigned k) {
    unsigned u = (k & 0x80000000u) ? (k ^ 0x80000000u) : ~k;
    return __uint_as_float(u);
}

// ============================================================================
// K1: per (row, chunk) exact top-256 (value desc, idx asc), sorted, u64 keys
// ============================================================================
__global__ __launch_bounds__(512, 8)
void k1_topk_chunk(const float* __restrict__ logits,
                   unsigned long long* __restrict__ ws_cand)
{
    __shared__ unsigned hist[BINS];
    __shared__ unsigned part[512];
    __shared__ unsigned long long cand[CAP];
    __shared__ unsigned ccount;
    __shared__ int s_tgrp;
    __shared__ unsigned s_sufnext;
    __shared__ int s_tbin;

    const int tid = threadIdx.x;
    const int row = blockIdx.x >> 3;            // NCHUNK == 8
    const int chunk = blockIdx.x & (NCHUNK - 1);
    const float4* rp4 = reinterpret_cast<const float4*>(
        logits + (size_t)row * VOCAB + (size_t)chunk * CHUNK);
    constexpr int N4 = CHUNK / 4;               // 4000

    for (int i = tid; i < BINS; i += 512) hist[i] = 0u;
    if (tid == 0) ccount = 0u;
    __syncthreads();

    // ---- load chunk into registers (one HBM sweep), histogram top-13 bits ----
    float4 r[8];
    #pragma unroll
    for (int it = 0; it < 8; ++it) {
        const int i = tid + it * 512;
        if (i < N4) r[it] = rp4[i];
    }
    #pragma unroll
    for (int it = 0; it < 8; ++it) {
        const int i = tid + it * 512;
        if (i < N4) {
            atomicAdd(&hist[mono(__float_as_uint(r[it].x)) >> SHIFT], 1u);
            atomicAdd(&hist[mono(__float_as_uint(r[it].y)) >> SHIFT], 1u);
            atomicAdd(&hist[mono(__float_as_uint(r[it].z)) >> SHIFT], 1u);
            atomicAdd(&hist[mono(__float_as_uint(r[it].w)) >> SHIFT], 1u);
        }
    }
    __syncthreads();

    // ---- group sums of 16 bins each (rotated reads: ~2-way banks, free) ----
    {
        unsigned s = 0;
        #pragma unroll
        for (int i = 0; i < 16; ++i)
            s += hist[tid * 16 + ((i + tid) & 15)];
        part[tid] = s;
    }
    __syncthreads();

    // ---- parallel suffix scan (inclusive): part[g] = sum_{h>=g} part[h] ----
    for (int off = 1; off < 512; off <<= 1) {
        unsigned t = (tid + off < 512) ? part[tid + off] : 0u;
        __syncthreads();
        part[tid] += t;
        __syncthreads();
    }

    // ---- threshold group: unique g with suf[g] >= K and suf[g+1] < K ----
    if (part[tid] >= (unsigned)K && (tid == 511 || part[tid + 1] < (unsigned)K)) {
        s_tgrp = tid;
        s_sufnext = (tid == 511) ? 0u : part[tid + 1];
    }
    __syncthreads();

    // ---- threshold bin within group via 16-lane ballot (wave 0 only) ----
    if (tid < 64) {
        unsigned st = 0;
        const int G = s_tgrp;
        if (tid < 16) {
            st = s_sufnext;
            for (int i = 15; i >= tid; --i) st += hist[G * 16 + i];
        }
        unsigned long long m = __ballot(tid < 16 && st >= (unsigned)K);
        if (tid == 0) s_tbin = G * 16 + (63 - __builtin_clzll(m));
    }
    __syncthreads();

    // ---- collect candidates from registers (no re-read) ----
    const unsigned tb = (unsigned)s_tbin;
    const int gbase = chunk * CHUNK;
    #pragma unroll
    for (int it = 0; it < 8; ++it) {
        const int i = tid + it * 512;
        if (i < N4) {
            const int base = gbase + i * 4;
            const unsigned ka = mono(__float_as_uint(r[it].x));
            const unsigned kb = mono(__float_as_uint(r[it].y));
            const unsigned kc = mono(__float_as_uint(r[it].z));
            const unsigned kd = mono(__float_as_uint(r[it].w));
            if ((ka >> SHIFT) >= tb) { unsigned p = atomicAdd(&ccount, 1u); if (p < CAP) cand[p] = ((unsigned long long)ka << 32) | (unsigned)(~(base + 0)); }
            if ((kb >> SHIFT) >= tb) { unsigned p = atomicAdd(&ccount, 1u); if (p < CAP) cand[p] = ((unsigned long long)kb << 32) | (unsigned)(~(base + 1)); }
            if ((kc >> SHIFT) >= tb) { unsigned p = atomicAdd(&ccount, 1u); if (p < CAP) cand[p] = ((unsigned long long)kc << 32) | (unsigned)(~(base + 2)); }
            if ((kd >> SHIFT) >= tb) { unsigned p = atomicAdd(&ccount, 1u); if (p < CAP) cand[p] = ((unsigned long long)kd << 32) | (unsigned)(~(base + 3)); }
        }
    }
    __syncthreads();

    // ---- hybrid bitonic sort 512, descending: shfl for j<64, LDS for j>=64 ----
    const unsigned cc = (ccount < (unsigned)CAP) ? ccount : (unsigned)CAP;
    unsigned long long v = (tid < (int)cc) ? cand[tid] : 0ull;

    #pragma unroll
    for (int kk = 2; kk <= CAP; kk <<= 1) {
        for (int j = kk >> 1; j > 0; j >>= 1) {
            const bool keepMax = (((tid & kk) == 0) == ((tid & j) == 0));
            unsigned long long w;
            if (j >= 64) {
                __syncthreads();
                cand[tid] = v;
                __syncthreads();
                w = cand[tid ^ j];
            } else {
                w = __shfl_xor(v, j, 64);
            }
            v = keepMax ? (v >= w ? v : w) : (v <= w ? v : w);
        }
    }

    if (tid < K) ws_cand[(size_t)blockIdx.x * K + tid] = v;
}

// ============================================================================
// K2: per row merge 8 sorted runs (bitonic merge stages only) + pipeline
// ============================================================================
__global__ __launch_bounds__(1024)
void k2_merge(const float* __restrict__ params,
              const unsigned long long* __restrict__ ws_cand,
              float* __restrict__ ws_v, float* __restrict__ ws_csum,
              int* __restrict__ ws_idx, float* __restrict__ ws_p0)
{
    constexpr int N = NCHUNK * K;   // 2048
    __shared__ unsigned long long cand[N];
    __shared__ float red[K];
    __shared__ float sc[K];

    const int row = blockIdx.x;
    const int tid = threadIdx.x;

    // load; reverse odd runs so runs alternate desc/asc (valid bitonic state k=256)
    for (int i = tid; i < N; i += 1024) {
        const int c = i >> 8, pos = i & (K - 1);
        unsigned long long v = ws_cand[(size_t)row * N + i];
        const int dest = (c & 1) ? ((c << 8) | (K - 1 - pos)) : i;
        cand[dest] = v;
    }
    __syncthreads();

    // bitonic merge stages k = 512, 1024, 2048 (descending overall)
    for (int kk2 = 2 * K; kk2 <= N; kk2 <<= 1) {
        for (int j = kk2 >> 1; j > 0; j >>= 1) {
            for (int i = tid; i < N; i += 1024) {
                const int ixj = i ^ j;
                if (ixj > i) {
                    unsigned long long a = cand[i], b = cand[ixj];
                    bool sw = ((i & kk2) == 0) ? (a < b) : (a > b);
                    if (sw) { cand[i] = b; cand[ixj] = a; }
                }
            }
            __syncthreads();
        }
    }

    // pipeline on top-256: topk-mask -> /temp -> softmax -> cumsum
    const bool act = tid < K;
    const float topk_f = params[row * 3 + 0];
    const float temp   = params[row * 3 + 2];
    float v = 0.f;
    int myidx = 0;
    if (act) {
        unsigned long long c = cand[tid];
        float val = inv_mono((unsigned)(c >> 32));
        myidx = (int)(~(unsigned)c);
        float x = (((float)tid) >= topk_f) ? IGNORED_C : val;
        v = x / temp;
        red[tid] = v;
    }
    __syncthreads();
    for (int s = K / 2; s > 0; s >>= 1) {
        if (tid < s) red[tid] = fmaxf(red[tid], red[tid + s]);
        __syncthreads();
    }
    const float m = red[0];
    __syncthreads();
    const float e = act ? expf(v - m) : 0.f;
    if (act) red[tid] = e;
    __syncthreads();
    for (int s = K / 2; s > 0; s >>= 1) {
        if (tid < s) red[tid] += red[tid + s];
        __syncthreads();
    }
    const float ssum = red[0];
    __syncthreads();
    const float p = e / ssum;
    if (act) sc[tid] = p;
    __syncthreads();
    for (int off = 1; off < K; off <<= 1) {
        float t = 0.f;
        if (act && tid >= off) t = sc[tid - off];
        __syncthreads();
        if (act) sc[tid] += t;
        __syncthreads();
    }
    if (act) {
        ws_v[row * K + tid]    = v;
        ws_csum[row * K + tid] = sc[tid];
        ws_idx[row * K + tid]  = myidx;
    }
    if (tid == 0) ws_p0[row] = p;   // probs[0] == csum[0]
}

// ============================================================================
// K3: global-min(p0) -> top-p mask -> softmax -> cumsum -> sample
// ============================================================================
__global__ __launch_bounds__(K)
void k3_sample(const float* __restrict__ params,
               const float* __restrict__ rand_u,
               const float* __restrict__ ws_v,
               const float* __restrict__ ws_csum,
               const int* __restrict__ ws_idx,
               const float* __restrict__ ws_p0,
               int* __restrict__ out)
{
    __shared__ float red[K];
    __shared__ float sc[K];
    const int row = blockIdx.x;
    const int tid = threadIdx.x;

    red[tid] = ws_p0[tid];          // BATCH == 256 == blockDim
    __syncthreads();
    for (int s = K / 2; s > 0; s >>= 1) {
        if (tid < s) red[tid] = fminf(red[tid], red[tid + s]);
        __syncthreads();
    }
    const float tpe = fmaxf(red[0], params[row * 3 + 1]);
    __syncthreads();

    const float csum = ws_csum[row * K + tid];
    const float v0   = ws_v[row * K + tid];
    const float v2 = ((csum > tpe) && (tid != 0)) ? IGNORED_C : v0;
    red[tid] = v2;
    __syncthreads();
    for (int s = K / 2; s > 0; s >>= 1) {
        if (tid < s) red[tid] = fmaxf(red[tid], red[tid + s]);
        __syncthreads();
    }
    const float m = red[0];
    __syncthreads();
    const float e = expf(v2 - m);
    red[tid] = e;
    __syncthreads();
    for (int s = K / 2; s > 0; s >>= 1) {
        if (tid < s) red[tid] += red[tid + s];
        __syncthreads();
    }
    const float ssum = red[0];
    __syncthreads();
    const float p = e / ssum;
    sc[tid] = p;
    __syncthreads();
    for (int off = 1; off < K; off <<= 1) {
        float t = (tid >= off) ? sc[tid - off] : 0.f;
        __syncthreads();
        sc[tid] += t;
        __syncthreads();
    }
    const float ru = rand_u[row];
    red[tid] = (ru > sc[tid]) ? 1.f : 0.f;
    __syncthreads();
    for (int s = K / 2; s > 0; s >>= 1) {
        if (tid < s) red[tid] += red[tid + s];
        __syncthreads();
    }
    if (tid == 0) {
        int sel = (int)red[0];
        if (sel > K - 1) sel = K - 1;
        out[row] = ws_idx[row * K + sel];
    }
}

// ============================================================================
// Fallback (round-1 proven): single block per row, used only if ws too small
// ============================================================================
__global__ __launch_bounds__(1024)
void fb_stage1(const float* __restrict__ logits,
               const float* __restrict__ params,
               float* __restrict__ ws_v,
               float* __restrict__ ws_csum,
               int* __restrict__ ws_idx,
               float* __restrict__ ws_p0)
{
    __shared__ unsigned hist[FB_BINS];
    __shared__ unsigned gsum[128];
    __shared__ unsigned long long cand[FB_CAND];
    __shared__ unsigned ccount;
    __shared__ int tbin;
    __shared__ float sv[K];
    __shared__ float se[K];
    __shared__ int   sidx[K];
    __shared__ float sred;

    const int row = blockIdx.x;
    const int tid = threadIdx.x;
    const float4* rp4 = reinterpret_cast<const float4*>(logits + (size_t)row * VOCAB);

    for (int i = tid; i < FB_BINS; i += 1024) hist[i] = 0u;
    __syncthreads();
    for (int i = tid; i < VOCAB / 4; i += 1024) {
        float4 v = rp4[i];
        atomicAdd(&hist[mono(__float_as_uint(v.x)) >> SHIFT], 1u);
        atomicAdd(&hist[mono(__float_as_uint(v.y)) >> SHIFT], 1u);
        atomicAdd(&hist[mono(__float_as_uint(v.z)) >> SHIFT], 1u);
        atomicAdd(&hist[mono(__float_as_uint(v.w)) >> SHIFT], 1u);
    }
    __syncthreads();
    if (tid < 128) {
        unsigned s = 0;
        for (int i = 0; i < 64; ++i) s += hist[tid * 64 + i];
        gsum[tid] = s;
    }
    __syncthreads();
    if (tid == 0) {
        unsigned acc = 0;
        int g = 127;
        for (; g > 0; --g) {
            if (acc + gsum[g] >= (unsigned)K) break;
            acc += gsum[g];
        }
        int t = g * 64;
        for (int bin = g * 64 + 63; bin >= g * 64; --bin) {
            acc += hist[bin];
            if (acc >= (unsigned)K) { t = bin; break; }
        }
        tbin = t;
        ccount = 0u;
    }
    __syncthreads();
    const unsigned tb = (unsigned)tbin;
    for (int i = tid; i < VOCAB / 4; i += 1024) {
        float4 v = rp4[i];
        const int base = i * 4;
        unsigned kk[4] = { mono(__float_as_uint(v.x)), mono(__float_as_uint(v.y)),
                           mono(__float_as_uint(v.z)), mono(__float_as_uint(v.w)) };
        #pragma unroll
        for (int c = 0; c < 4; ++c) {
            if ((kk[c] >> SHIFT) >= tb) {
                unsigned p = atomicAdd(&ccount, 1u);
                if (p < FB_CAND)
                    cand[p] = ((unsigned long long)kk[c] << 32) | (unsigned)(~(base + c));
            }
        }
    }
    __syncthreads();
    for (int i = tid; i < FB_CAND; i += 1024)
        if ((unsigned)i >= ccount) cand[i] = 0ull;
    __syncthreads();
    for (int k = 2; k <= FB_CAND; k <<= 1) {
        for (int j = k >> 1; j > 0; j >>= 1) {
            for (int i = tid; i < FB_CAND; i += 1024) {
                int ixj = i ^ j;
                if (ixj > i) {
                    unsigned long long a = cand[i], b = cand[ixj];
                    bool sw = ((i & k) == 0) ? (a < b) : (a > b);
                    if (sw) { cand[i] = b; cand[ixj] = a; }
                }
            }
            __syncthreads();
        }
    }
    const float topk_f = params[row * 3 + 0];
    const float temp   = params[row * 3 + 2];
    if (tid < K) {
        unsigned long long c = cand[tid];
        float val = inv_mono((unsigned)(c >> 32));
        sidx[tid] = (int)(~(unsigned)c);
        float v = (((float)tid) >= topk_f) ? IGNORED_C : val;
        sv[tid] = v / temp;
    }
    __syncthreads();
    if (tid == 0) {
        float mm = sv[0];
        for (int i = 1; i < K; ++i) mm = fmaxf(mm, sv[i]);
        sred = mm;
    }
    __syncthreads();
    if (tid < K) se[tid] = expf(sv[tid] - sred);
    __syncthreads();
    if (tid == 0) {
        float s = 0.f;
        for (int i = 0; i < K; ++i) s += se[i];
        sred = s;
    }
    __syncthreads();
    if (tid < K) se[tid] = se[tid] / sred;
    __syncthreads();
    if (tid == 0) {
        float c = 0.f;
        for (int i = 0; i < K; ++i) { c += se[i]; se[i] = c; }
    }
    __syncthreads();
    if (tid < K) {
        ws_v[row * K + tid]    = sv[tid];
        ws_csum[row * K + tid] = se[tid];
        ws_idx[row * K + tid]  = sidx[tid];
    }
    if (tid == 0) ws_p0[row] = se[0];
}

extern "C" void kernel_launch(void* const* d_in, const int* in_sizes, int n_in,
                              void* d_out, int out_size, void* d_ws, size_t ws_size,
                              hipStream_t stream) {
    const float* logits = (const float*)d_in[0];
    const float* params = (const float*)d_in[1];
    const float* randu  = (const float*)d_in[2];
    int* out = (int*)d_out;
    char* ws = (char*)d_ws;

    const size_t cand_bytes = (size_t)BATCH * NCHUNK * K * 8;          // 4 MB
    const size_t tail_bytes = (size_t)3 * BATCH * K * 4 + BATCH * 4;   // 769 KB
    if (ws_size >= cand_bytes + tail_bytes) {
        unsigned long long* ws_cand = (unsigned long long*)ws;
        char* p = ws + cand_bytes;
        float* ws_v    = (float*)(p);
        float* ws_csum = (float*)(p + (size_t)BATCH * K * 4);
        int*   ws_idx  = (int*)  (p + (size_t)2 * BATCH * K * 4);
        float* ws_p0   = (float*)(p + (size_t)3 * BATCH * K * 4);
        hipLaunchKernelGGL(k1_topk_chunk, dim3(BATCH * NCHUNK), dim3(512), 0, stream,
                           logits, ws_cand);
        hipLaunchKernelGGL(k2_merge, dim3(BATCH), dim3(1024), 0, stream,
                           params, ws_cand, ws_v, ws_csum, ws_idx, ws_p0);
        hipLaunchKernelGGL(k3_sample, dim3(BATCH), dim3(K), 0, stream,
                           params, randu, ws_v, ws_csum, ws_idx, ws_p0, out);
    } else {
        float* ws_v    = (float*)(ws);
        float* ws_csum = (float*)(ws + (size_t)BATCH * K * 4);
        int*   ws_idx  = (int*)  (ws + (size_t)2 * BATCH * K * 4);
        float* ws_p0   = (float*)(ws + (size_t)3 * BATCH * K * 4);
        hipLaunchKernelGGL(fb_stage1, dim3(BATCH), dim3(1024), 0, stream,
                           logits, params, ws_v, ws_csum, ws_idx, ws_p0);
        hipLaunchKernelGGL(k3_sample, dim3(BATCH), dim3(K), 0, stream,
                           params, randu, ws_v, ws_csum, ws_idx, ws_p0, out);
    }
}